// Round 3
// baseline (230.668 us; speedup 1.0000x reference)
//
#include <hip/hip_runtime.h>
#include <hip/hip_bf16.h>
#include <cstdint>

#define NN 2048
#define NH 4
#define NW 64   // mask words per row

typedef __attribute__((ext_vector_type(8))) short bf16x8;
typedef __attribute__((ext_vector_type(4))) float f32x4;
typedef __attribute__((ext_vector_type(4))) unsigned short u16x4;

__device__ __forceinline__ float lrelu(float s) { return s > 0.f ? s : 0.2f * s; }

__device__ __forceinline__ unsigned pk2(float lo, float hi) {
  __hip_bfloat162 h2 = __float22bfloat162_rn(make_float2(lo, hi));
  union { __hip_bfloat162 h; unsigned u; } c; c.h = h2; return c.u;
}
__device__ __forceinline__ short f2bf1(float f) {
  __hip_bfloat16 h = __float2bfloat16(f);
  union { __hip_bfloat16 h; unsigned short u; } c; c.h = h; return (short)c.u;
}
__device__ __forceinline__ bf16x8 cvt8(f32x4 v0, f32x4 v1) {
  union { unsigned u[4]; bf16x8 v; } r;
  r.u[0] = pk2(v0[0], v0[1]); r.u[1] = pk2(v0[2], v0[3]);
  r.u[2] = pk2(v1[0], v1[1]); r.u[3] = pk2(v1[2], v1[3]);
  return r.v;
}

// ---------- kA: blocks [0,16384): pack adj bits; [16384,16896): proj1 ----------
__global__ __launch_bounds__(256) void kA(
    const int* __restrict__ adj, unsigned* __restrict__ mb,
    const float* __restrict__ x, const float* __restrict__ W1,
    const float* __restrict__ a1, unsigned short* __restrict__ wht1,
    float* __restrict__ ssrc1, float* __restrict__ G1g, float* __restrict__ G2g,
    unsigned* __restrict__ mx1u) {
  if (blockIdx.x < 16384) {
    int gid = blockIdx.x * 256 + threadIdx.x;       // one int4 per thread
    const int4 v = ((const int4*)adj)[gid];
    unsigned nib = (unsigned)(v.x != 0) | ((unsigned)(v.y != 0) << 1) |
                   ((unsigned)(v.z != 0) << 2) | ((unsigned)(v.w != 0) << 3);
    unsigned wv = nib << (4 * (threadIdx.x & 7));
    wv |= __shfl_xor(wv, 1); wv |= __shfl_xor(wv, 2); wv |= __shfl_xor(wv, 4);
    if ((threadIdx.x & 7) == 0) mb[gid >> 3] = wv;
    return;
  }
  int blk = blockIdx.x - 16384;        // 0..511, 16 rows each
  int rowg = blk * 16;
  int b = rowg >> 11, rloc = rowg & (NN - 1);
  int tid = threadIdx.x, lane = tid & 63, h = tid >> 6;
  int cl = lane & 15, g = lane >> 4;

  const float* xr = x + (size_t)(rowg + cl) * 64 + 8 * g;
  bf16x8 af[2];
#pragma unroll
  for (int ks = 0; ks < 2; ++ks)
    af[ks] = cvt8(*(const f32x4*)(xr + ks * 32), *(const f32x4*)(xr + ks * 32 + 4));

  f32x4 zero = {0.f, 0.f, 0.f, 0.f};
  f32x4 acc[4] = {zero, zero, zero, zero};
#pragma unroll
  for (int ft = 0; ft < 4; ++ft) {
    const float* wr = W1 + (size_t)(h * 64 + ft * 16 + cl) * 64 + 8 * g;
#pragma unroll
    for (int ks = 0; ks < 2; ++ks) {
      bf16x8 bfr = cvt8(*(const f32x4*)(wr + ks * 32), *(const f32x4*)(wr + ks * 32 + 4));
      acc[ft] = __builtin_amdgcn_mfma_f32_16x16x32_bf16(af[ks], bfr, acc[ft], 0, 0, 0);
    }
  }
  float ps[4] = {0.f, 0.f, 0.f, 0.f}, pd[4] = {0.f, 0.f, 0.f, 0.f};
#pragma unroll
  for (int ft = 0; ft < 4; ++ft) {
    float as = a1[h * 128 + ft * 16 + cl];
    float ad = a1[h * 128 + 64 + ft * 16 + cl];
    u16x4 w4;
#pragma unroll
    for (int r = 0; r < 4; ++r) {
      float v = acc[ft][r];                       // row rloc+4g+r, col ft*16+cl
      w4[r] = (unsigned short)f2bf1(v);
      ps[r] += v * as; pd[r] += v * ad;
    }
    *(u16x4*)(wht1 + (size_t)((b * NH + h) * 64 + ft * 16 + cl) * NN + rloc + 4 * g) = w4;
  }
  float gm = 0.f;
#pragma unroll
  for (int r = 0; r < 4; ++r) {
    float s = ps[r], d = pd[r];
    s += __shfl_xor(s, 1); s += __shfl_xor(s, 2); s += __shfl_xor(s, 4); s += __shfl_xor(s, 8);
    d += __shfl_xor(d, 1); d += __shfl_xor(d, 2); d += __shfl_xor(d, 4); d += __shfl_xor(d, 8);
    float g1v = __expf(d);
    gm = fmaxf(gm, g1v);
    if (cl == 0) {
      int idx = (b * NH + h) * NN + rloc + 4 * g + r;
      ssrc1[idx] = s;
      G1g[idx] = g1v;
      G2g[idx] = __expf(0.2f * d);
    }
  }
  gm = fmaxf(gm, __shfl_xor(gm, 16));
  gm = fmaxf(gm, __shfl_xor(gm, 32));
  if (lane == 0) atomicMax(&mx1u[b * NH + h], __float_as_uint(gm));
}

// ---------- k2: layer-1 attention. block = 64 rows, 8 waves = 4 rowtiles x 2 jhalves
__global__ __launch_bounds__(512) void k2_attn1(
    const unsigned short* __restrict__ wht1, const float* __restrict__ ssrc1,
    const float* __restrict__ G1g, const float* __restrict__ G2g,
    const unsigned* __restrict__ mb, const unsigned* __restrict__ mx1u,
    float* __restrict__ hout) {
  // phase 1: sdm[64][65] (16640 B) + sG1[2048] (8 KB) + sG2[2048] (8 KB) = 33024 B
  // phase 2 (overlay): cmb[4][16][68] (17408 B) + sden[4][16] (256 B)
  __shared__ __align__(16) char smem[33024];
  unsigned (*sdm)[65] = (unsigned(*)[65])smem;
  float* sG1 = (float*)(smem + 16640);
  float* sG2 = (float*)(smem + 16640 + 8192);
  float (*cmb)[16][68] = (float(*)[16][68])smem;
  float (*sden)[16] = (float(*)[16])(smem + 17408);

  int blk = blockIdx.x;                // 512 = [b(4)][h(4)][tile(32)]
  int tile = blk & 31, h = (blk >> 5) & 3, b = blk >> 7;
  int rowblk = tile << 6;
  int t = threadIdx.x, lane = t & 63, w = t >> 6;
  int wloc = w & 3, jh = w >> 2;
  int cl = lane & 15, g = lane >> 4, g8 = g * 8;

  { // stage 64 rows x 64 mask words (coalesced 128B per 8 threads)
    int row = t >> 3, c = (t & 7) * 4;
    const unsigned* mrow = mb + (size_t)(b * NN + rowblk + row) * NW;
    uint4 v0 = *(const uint4*)(mrow + c);
    uint4 v1 = *(const uint4*)(mrow + 32 + c);
    sdm[row][c + 0] = v0.x; sdm[row][c + 1] = v0.y;
    sdm[row][c + 2] = v0.z; sdm[row][c + 3] = v0.w;
    sdm[row][32 + c + 0] = v1.x; sdm[row][32 + c + 1] = v1.y;
    sdm[row][32 + c + 2] = v1.z; sdm[row][32 + c + 3] = v1.w;
  }
  { // stage G1/G2 (full 2048 each)
    const f32x4* g1p = (const f32x4*)(G1g + (size_t)(b * NH + h) * NN);
    const f32x4* g2p = (const f32x4*)(G2g + (size_t)(b * NH + h) * NN);
    ((f32x4*)sG1)[t] = g1p[t];
    ((f32x4*)sG2)[t] = g2p[t];
  }
  float logMx = __logf(__uint_as_float(mx1u[b * NH + h]));
  int rowW = rowblk + wloc * 16;
  float s = ssrc1[(size_t)(b * NH + h) * NN + rowW + cl];
  float m = lrelu(s + logMx);          // upper bound of row max of lrelu(s+t)
  float F1 = __expf(s - m), F2 = __expf(0.2f * s - m);
  __syncthreads();

  short onev = (cl == 0) ? (short)0x3F80 : (short)0;
  bf16x8 ones = {onev, onev, onev, onev, onev, onev, onev, onev};
  f32x4 zero = {0.f, 0.f, 0.f, 0.f};
  f32x4 acc[4] = {zero, zero, zero, zero};
  f32x4 acc1 = zero;                   // denominator via ones column
  const unsigned short* whb = wht1 + (size_t)((b * NH + h) * 64) * NN;
  int rloc = wloc * 16 + cl;

  for (int kb = jh * 32; kb < jh * 32 + 32; ++kb) {
    unsigned by = (sdm[rloc][kb] >> g8) & 0xFFu;
    int j0 = kb * 32 + g8;
    f32x4 g1a = *(const f32x4*)(sG1 + j0);
    f32x4 g1b = *(const f32x4*)(sG1 + j0 + 4);
    f32x4 g2a = *(const f32x4*)(sG2 + j0);
    f32x4 g2b = *(const f32x4*)(sG2 + j0 + 4);
    float wv[8];
#pragma unroll
    for (int e = 0; e < 8; ++e) {
      float g1 = (e < 4) ? g1a[e] : g1b[e - 4];
      float g2 = (e < 4) ? g2a[e] : g2b[e - 4];
      float v = fmaxf(F1 * g1, F2 * g2);   // exp(lrelu(s+t)-m), branch-free
      wv[e] = ((by >> e) & 1u) ? v : 0.f;
    }
    union { unsigned u[4]; bf16x8 v; } pa;
    pa.u[0] = pk2(wv[0], wv[1]); pa.u[1] = pk2(wv[2], wv[3]);
    pa.u[2] = pk2(wv[4], wv[5]); pa.u[3] = pk2(wv[6], wv[7]);
#pragma unroll
    for (int ft = 0; ft < 4; ++ft) {
      bf16x8 bf = *(const bf16x8*)(whb + (size_t)(ft * 16 + cl) * NN + j0);
      acc[ft] = __builtin_amdgcn_mfma_f32_16x16x32_bf16(pa.v, bf, acc[ft], 0, 0, 0);
    }
    acc1 = __builtin_amdgcn_mfma_f32_16x16x32_bf16(pa.v, ones, acc1, 0, 0, 0);
  }
  __syncthreads();                     // all reads of sdm/sG done; overlay safe
  if (jh == 1) {
#pragma unroll
    for (int ft = 0; ft < 4; ++ft)
#pragma unroll
      for (int r = 0; r < 4; ++r)
        cmb[wloc][4 * g + r][ft * 16 + cl] = acc[ft][r];
    if (cl == 0) {
#pragma unroll
      for (int r = 0; r < 4; ++r) sden[wloc][4 * g + r] = acc1[r];
    }
  }
  __syncthreads();
  if (jh == 0) {
#pragma unroll
    for (int r = 0; r < 4; ++r) {
      int rowm = 4 * g + r;
      float dself = __shfl(acc1[r], lane & 48);   // cl==0 lane of this g-group
      float inv = 1.f / (dself + sden[wloc][rowm]);
      float* dst = hout + (size_t)(b * NN + rowW + rowm) * 256 + h * 64;
#pragma unroll
      for (int ft = 0; ft < 4; ++ft) {
        float v = (acc[ft][r] + cmb[wloc][rowm][ft * 16 + cl]) * inv;
        v = v > 0.f ? v : (__expf(v) - 1.f);      // ELU
        dst[ft * 16 + cl] = v;
      }
    }
  }
}

// ---------- k3: Wh2 = h @ W2^T via MFMA split-K; scores + G factors ------------
__global__ __launch_bounds__(256) void k3_proj2(
    const float* __restrict__ hin, const float* __restrict__ W2,
    const float* __restrict__ a2, unsigned short* __restrict__ wh2t,
    float* __restrict__ ssrc2, float* __restrict__ G1o, float* __restrict__ G2o,
    unsigned* __restrict__ mx2u) {
  __shared__ float cmb[4][16][33];
  int blk = blockIdx.x;                 // 512: 16 rows each
  int b = blk >> 7, rowbase = (blk & 127) << 4;
  int t = threadIdx.x, lane = t & 63, w = t >> 6;
  int cl = lane & 15, g = lane >> 4;
  int k0 = w * 64;                      // K split across 4 waves

  const float* hr = hin + (size_t)(b * NN + rowbase + cl) * 256 + k0 + 8 * g;
  bf16x8 af[2];
#pragma unroll
  for (int ks = 0; ks < 2; ++ks)
    af[ks] = cvt8(*(const f32x4*)(hr + ks * 32), *(const f32x4*)(hr + ks * 32 + 4));

  f32x4 zero = {0.f, 0.f, 0.f, 0.f};
  f32x4 acc[2] = {zero, zero};
#pragma unroll
  for (int ft = 0; ft < 2; ++ft) {
    const float* wr = W2 + (size_t)(ft * 16 + cl) * 256 + k0 + 8 * g;
#pragma unroll
    for (int ks = 0; ks < 2; ++ks) {
      bf16x8 bfr = cvt8(*(const f32x4*)(wr + ks * 32), *(const f32x4*)(wr + ks * 32 + 4));
      acc[ft] = __builtin_amdgcn_mfma_f32_16x16x32_bf16(af[ks], bfr, acc[ft], 0, 0, 0);
    }
  }
#pragma unroll
  for (int ft = 0; ft < 2; ++ft)
#pragma unroll
    for (int r = 0; r < 4; ++r)
      cmb[w][4 * g + r][ft * 16 + cl] = acc[ft][r];
  __syncthreads();

  int row = t >> 4, c0 = t & 15;
  float v0 = cmb[0][row][c0] + cmb[1][row][c0] + cmb[2][row][c0] + cmb[3][row][c0];
  float v1 = cmb[0][row][c0 + 16] + cmb[1][row][c0 + 16] + cmb[2][row][c0 + 16] + cmb[3][row][c0 + 16];
  float ps = v0 * a2[c0] + v1 * a2[c0 + 16];
  float pd = v0 * a2[32 + c0] + v1 * a2[32 + c0 + 16];
  ps += __shfl_xor(ps, 1); ps += __shfl_xor(ps, 2); ps += __shfl_xor(ps, 4); ps += __shfl_xor(ps, 8);
  pd += __shfl_xor(pd, 1); pd += __shfl_xor(pd, 2); pd += __shfl_xor(pd, 4); pd += __shfl_xor(pd, 8);
  if (c0 == 0) {
    int idx = b * NN + rowbase + row;
    ssrc2[idx] = ps;
    float g1v = __expf(pd);
    G1o[idx] = g1v;
    G2o[idx] = __expf(0.2f * pd);
    atomicMax(&mx2u[b], __float_as_uint(g1v));
  }
  cmb[0][row][c0] = v0;          // own location: read-then-write, no cross-thread hazard
  cmb[0][row][c0 + 16] = v1;
  __syncthreads();
  int col = t >> 3, rg = t & 7;  // transposed bf16 store, 2 nodes per thread
  unsigned pk = pk2(cmb[0][2 * rg][col], cmb[0][2 * rg + 1][col]);
  *(unsigned*)(wh2t + (size_t)(b * 32 + col) * NN + rowbase + 2 * rg) = pk;
}

// ---------- k4: layer-2 attention. block = 16 rows, 4 waves split columns ------
__global__ __launch_bounds__(256) void k4_attn2(
    const unsigned short* __restrict__ wh2t, const float* __restrict__ ssrc2,
    const float* __restrict__ G1o, const float* __restrict__ G2o,
    const unsigned* __restrict__ mb, const unsigned* __restrict__ mx2u,
    float* __restrict__ outp) {
  __shared__ unsigned sdm[16][65];
  __shared__ __align__(16) float sG1[NN];
  __shared__ __align__(16) float sG2[NN];
  __shared__ float cmb[4][16][36];
  __shared__ float cden[4][16];
  int blk = blockIdx.x;                // 512: 16 rows each
  int b = blk >> 7, rowbase = (blk & 127) << 4;
  int t = threadIdx.x, lane = t & 63, w = t >> 6;
  int cl = lane & 15, g = lane >> 4, g8 = g * 8;
  {
    int row = t >> 4, c = (t & 15) * 4;
    uint4 v = *(const uint4*)(mb + (size_t)(b * NN + rowbase + row) * NW + c);
    sdm[row][c + 0] = v.x; sdm[row][c + 1] = v.y;
    sdm[row][c + 2] = v.z; sdm[row][c + 3] = v.w;
  }
  {
    const f32x4* g1p = (const f32x4*)(G1o + (size_t)b * NN);
    const f32x4* g2p = (const f32x4*)(G2o + (size_t)b * NN);
    ((f32x4*)sG1)[t] = g1p[t]; ((f32x4*)sG1)[t + 256] = g1p[t + 256];
    ((f32x4*)sG2)[t] = g2p[t]; ((f32x4*)sG2)[t + 256] = g2p[t + 256];
  }
  float logMx = __logf(__uint_as_float(mx2u[b]));
  float s = ssrc2[b * NN + rowbase + cl];
  float m = lrelu(s + logMx);
  float F1 = __expf(s - m), F2 = __expf(0.2f * s - m);
  __syncthreads();

  short onev = (cl == 0) ? (short)0x3F80 : (short)0;
  bf16x8 ones = {onev, onev, onev, onev, onev, onev, onev, onev};
  f32x4 zero = {0.f, 0.f, 0.f, 0.f};
  f32x4 acc[2] = {zero, zero};
  f32x4 acc1 = zero;
  const unsigned short* whb = wh2t + (size_t)(b * 32) * NN;

  for (int kb = w * 16; kb < w * 16 + 16; ++kb) {
    unsigned by = (sdm[cl][kb] >> g8) & 0xFFu;
    int j0 = kb * 32 + g8;
    f32x4 g1a = *(const f32x4*)(sG1 + j0);
    f32x4 g1b = *(const f32x4*)(sG1 + j0 + 4);
    f32x4 g2a = *(const f32x4*)(sG2 + j0);
    f32x4 g2b = *(const f32x4*)(sG2 + j0 + 4);
    float wv[8];
#pragma unroll
    for (int e = 0; e < 8; ++e) {
      float g1 = (e < 4) ? g1a[e] : g1b[e - 4];
      float g2 = (e < 4) ? g2a[e] : g2b[e - 4];
      float v = fmaxf(F1 * g1, F2 * g2);
      wv[e] = ((by >> e) & 1u) ? v : 0.f;
    }
    union { unsigned u[4]; bf16x8 v; } pa;
    pa.u[0] = pk2(wv[0], wv[1]); pa.u[1] = pk2(wv[2], wv[3]);
    pa.u[2] = pk2(wv[4], wv[5]); pa.u[3] = pk2(wv[6], wv[7]);
#pragma unroll
    for (int ft = 0; ft < 2; ++ft) {
      bf16x8 bf = *(const bf16x8*)(whb + (size_t)(ft * 16 + cl) * NN + j0);
      acc[ft] = __builtin_amdgcn_mfma_f32_16x16x32_bf16(pa.v, bf, acc[ft], 0, 0, 0);
    }
    acc1 = __builtin_amdgcn_mfma_f32_16x16x32_bf16(pa.v, ones, acc1, 0, 0, 0);
  }
#pragma unroll
  for (int ft = 0; ft < 2; ++ft)
#pragma unroll
    for (int r = 0; r < 4; ++r)
      cmb[w][4 * g + r][ft * 16 + cl] = acc[ft][r];
  if (cl == 0) {
#pragma unroll
    for (int r = 0; r < 4; ++r) cden[w][4 * g + r] = acc1[r];
  }
  __syncthreads();
  int row = t >> 4, c0 = t & 15;
  float n0 = cmb[0][row][c0] + cmb[1][row][c0] + cmb[2][row][c0] + cmb[3][row][c0];
  float n1 = cmb[0][row][c0 + 16] + cmb[1][row][c0 + 16] + cmb[2][row][c0 + 16] + cmb[3][row][c0 + 16];
  float den = cden[0][row] + cden[1][row] + cden[2][row] + cden[3][row];
  float inv = 1.f / den;
  float* dst = outp + (size_t)(b * NN + rowbase + row) * 32;
  dst[c0] = n0 * inv;
  dst[c0 + 16] = n1 * inv;
}

extern "C" void kernel_launch(void* const* d_in, const int* in_sizes, int n_in,
                              void* d_out, int out_size, void* d_ws, size_t ws_size,
                              hipStream_t stream) {
  (void)in_sizes; (void)n_in; (void)out_size; (void)ws_size;
  const float* x   = (const float*)d_in[0];
  const int*   adj = (const int*)d_in[1];
  const float* W1  = (const float*)d_in[2];
  const float* a1  = (const float*)d_in[3];
  const float* W2  = (const float*)d_in[4];
  const float* a2  = (const float*)d_in[5];
  float* outp = (float*)d_out;
  char* ws = (char*)d_ws;

  unsigned*       mbits = (unsigned*)(ws);                                   // 2 MB
  unsigned short* wht1  = (unsigned short*)(ws + (size_t)(2u << 20));        // 4 MB
  float*          ssrc1 = (float*)(ws + (size_t)(6u << 20));                 // 128 KB
  float*          G1g   = (float*)(ws + (size_t)(6u << 20) + (128u << 10));  // 128 KB
  float*          G2g   = (float*)(ws + (size_t)(6u << 20) + (256u << 10));  // 128 KB
  float*          hbuf  = (float*)(ws + (size_t)(6u << 20) + (512u << 10));  // 8 MB
  unsigned short* wh2t  = (unsigned short*)(ws + (size_t)(14u << 20) + (512u << 10)); // 512 KB
  float*          ssrc2 = (float*)(ws + (size_t)(15u << 20));                // 32 KB
  float*          G1o   = (float*)(ws + (size_t)(15u << 20) + (32u << 10));  // 32 KB
  float*          G2o   = (float*)(ws + (size_t)(15u << 20) + (64u << 10));  // 32 KB
  unsigned*       mx1u  = (unsigned*)(ws + (size_t)(15u << 20) + (96u << 10)); // 64 B
  unsigned*       mx2u  = mx1u + 16;                                           // 16 B

  hipMemsetAsync(mx1u, 0, 128, stream);
  kA      <<<16896, 256, 0, stream>>>(adj, mbits, x, W1, a1, wht1, ssrc1, G1g, G2g, mx1u);
  k2_attn1<<<512,   512, 0, stream>>>(wht1, ssrc1, G1g, G2g, mbits, mx1u, hbuf);
  k3_proj2<<<512,   256, 0, stream>>>(hbuf, W2, a2, wh2t, ssrc2, G1o, G2o, mx2u);
  k4_attn2<<<512,   256, 0, stream>>>(wh2t, ssrc2, G1o, G2o, mbits, mx2u, outp);
}